// Round 1
// baseline (394.541 us; speedup 1.0000x reference)
//
#include <hip/hip_runtime.h>
#include <math.h>

typedef _Float16 f16;
typedef _Float16 f16x8 __attribute__((ext_vector_type(8)));
typedef float f32x4 __attribute__((ext_vector_type(4)));

#define LDS_STRIDE 136  // 128 + 8 f16 pad -> 272B rows, 16B aligned, conflict-free b128

// ---------------------------------------------------------------------------
// Kernel A: per-point MLP layers 1-2 (fp32 compute), store h2 as f16 [pt][128]
// ---------------------------------------------------------------------------
__global__ __launch_bounds__(256) void pointnet_l12(
    const float* __restrict__ x,
    const float* __restrict__ W1, const float* __restrict__ b1,
    const float* __restrict__ W2, const float* __restrict__ b2,
    f16* __restrict__ h2)
{
    int p = blockIdx.x * 256 + threadIdx.x;  // 262144 points
    float x0 = x[3*p], x1 = x[3*p+1], x2 = x[3*p+2];
    float h1[64];
#pragma unroll
    for (int j = 0; j < 64; j++) {
        float a = fmaf(x2, W1[128+j], fmaf(x1, W1[64+j], fmaf(x0, W1[j], b1[j])));
        h1[j] = fmaxf(a, 0.f);
    }
#pragma unroll 1
    for (int c0 = 0; c0 < 128; c0 += 8) {
        float acc[8];
#pragma unroll
        for (int j = 0; j < 8; j++) acc[j] = b2[c0+j];
#pragma unroll
        for (int k = 0; k < 64; k++) {
#pragma unroll
            for (int j = 0; j < 8; j++)
                acc[j] = fmaf(h1[k], W2[k*128 + c0 + j], acc[j]);
        }
        f16x8 o;
#pragma unroll
        for (int j = 0; j < 8; j++) o[j] = (f16)fmaxf(acc[j], 0.f);
        *(f16x8*)(h2 + (size_t)p*128 + c0) = o;
    }
}

// ---------------------------------------------------------------------------
// Prep: W3 [128][1024] fp32 -> W3T f16 [1024 n][128 k]  (B-fragment layout)
// ---------------------------------------------------------------------------
__global__ void prep_w3t(const float* __restrict__ w3, f16* __restrict__ w3t)
{
    int idx = blockIdx.x * 256 + threadIdx.x;  // 131072
    int n = idx >> 7, k = idx & 127;
    w3t[idx] = (f16)w3[k*1024 + n];
}

// ---------------------------------------------------------------------------
// Kernel B: per batch, h2[1024x128] @ W3[128x1024] (f16 MFMA), relu+bias,
// max over points -> g[B][1024]. Block = (batch, 128-col tile), 4 waves 2x2.
// B-fragments (full K) live in registers for the whole kernel.
// ---------------------------------------------------------------------------
__global__ __launch_bounds__(256, 2) void pointnet_l3_max(
    const f16* __restrict__ h2,    // [B*1024][128]
    const f16* __restrict__ w3t,   // [1024][128]
    const float* __restrict__ b3,  // [1024]
    float* __restrict__ g)         // [B][1024]
{
    __shared__ __align__(16) f16 atile[128 * LDS_STRIDE];  // 34816 B
    __shared__ float redbuf[4][64];

    int nb  = blockIdx.x;          // 0..7 col block
    int b   = blockIdx.y;          // 0..255 batch
    int tid = threadIdx.x;
    int lane = tid & 63, wid = tid >> 6;
    int wr = wid & 1, wc = wid >> 1;
    int lrow = lane & 15, quad = lane >> 4;
    int col0 = nb*128 + wc*64;

    // Load B-fragments: 4 col-tiles x 4 k-chunks, 16B each (64 VGPRs)
    f16x8 bf[4][4];
#pragma unroll
    for (int ct = 0; ct < 4; ct++)
#pragma unroll
        for (int kc = 0; kc < 4; kc++)
            bf[ct][kc] = *(const f16x8*)(w3t + (size_t)(col0 + ct*16 + lrow)*128 + kc*32 + quad*8);

    float cmax[4] = {-3.0e38f, -3.0e38f, -3.0e38f, -3.0e38f};
    const f16* abase = h2 + (size_t)b * 1024 * 128;

    for (int m0 = 0; m0 < 1024; m0 += 128) {
        __syncthreads();
        // stage A m-tile: 128 rows x 128 k, f16, padded rows
#pragma unroll
        for (int i = 0; i < 8; i++) {
            int e = tid + i*256;               // 2048 chunks of 16B
            int row = e >> 4, cch = e & 15;
            *(f16x8*)(atile + row*LDS_STRIDE + cch*8) =
                *(const f16x8*)(abase + (size_t)(m0+row)*128 + cch*8);
        }
        __syncthreads();

        f32x4 acc[4][4];
#pragma unroll
        for (int rt = 0; rt < 4; rt++)
#pragma unroll
            for (int ct = 0; ct < 4; ct++)
                acc[rt][ct] = (f32x4){0.f, 0.f, 0.f, 0.f};

#pragma unroll
        for (int kc = 0; kc < 4; kc++) {
            f16x8 af[4];
#pragma unroll
            for (int rt = 0; rt < 4; rt++)
                af[rt] = *(const f16x8*)(atile + (wr*64 + rt*16 + lrow)*LDS_STRIDE + kc*32 + quad*8);
#pragma unroll
            for (int rt = 0; rt < 4; rt++)
#pragma unroll
                for (int ct = 0; ct < 4; ct++)
                    acc[rt][ct] = __builtin_amdgcn_mfma_f32_16x16x32_f16(af[rt], bf[ct][kc], acc[rt][ct], 0, 0, 0);
        }
        // fold rows into running col-max (bias+relu deferred: monotone)
#pragma unroll
        for (int rt = 0; rt < 4; rt++)
#pragma unroll
            for (int ct = 0; ct < 4; ct++)
#pragma unroll
                for (int r = 0; r < 4; r++)
                    cmax[ct] = fmaxf(cmax[ct], acc[rt][ct][r]);
    }

    // reduce across quads (rows split by quad): lanes L, L^16, L^32
#pragma unroll
    for (int ct = 0; ct < 4; ct++) {
        cmax[ct] = fmaxf(cmax[ct], __shfl_xor(cmax[ct], 16, 64));
        cmax[ct] = fmaxf(cmax[ct], __shfl_xor(cmax[ct], 32, 64));
    }
    if (quad == 0) {
#pragma unroll
        for (int ct = 0; ct < 4; ct++) redbuf[wid][ct*16 + lrow] = cmax[ct];
    }
    __syncthreads();
    if (tid < 128) {
        int c = tid;                  // col within block
        int wcc = c >> 6;
        float v = fmaxf(redbuf[wcc*2][c & 63], redbuf[wcc*2+1][c & 63]);
        int gc = nb*128 + c;
        g[(size_t)b*1024 + gc] = fmaxf(v + b3[gc], 0.f);
    }
}

// ---------------------------------------------------------------------------
// SVD -> SO(3) projection, fp64 Jacobi on M^T M (per-thread serial)
// ---------------------------------------------------------------------------
__device__ inline void jrot(double S[3][3], double V[3][3], int p, int q)
{
    double apq = S[p][q];
    if (fabs(apq) < 1e-36) return;
    double tau = (S[q][q] - S[p][p]) / (2.0 * apq);
    double t = (tau >= 0.0 ? 1.0 : -1.0) / (fabs(tau) + sqrt(1.0 + tau*tau));
    double c = 1.0 / sqrt(1.0 + t*t);
    double s = t * c;
    for (int k = 0; k < 3; k++) {
        double skp = S[k][p], skq = S[k][q];
        S[k][p] = c*skp - s*skq;  S[k][q] = s*skp + c*skq;
    }
    for (int k = 0; k < 3; k++) {
        double spk = S[p][k], sqk = S[q][k];
        S[p][k] = c*spk - s*sqk;  S[q][k] = s*spk + c*sqk;
    }
    for (int k = 0; k < 3; k++) {
        double vkp = V[k][p], vkq = V[k][q];
        V[k][p] = c*vkp - s*vkq;  V[k][q] = s*vkp + c*vkq;
    }
}

__device__ void svd_so3(const float* Mf, float* Rout)
{
    double M[3][3], S[3][3], V[3][3];
    for (int i = 0; i < 3; i++)
        for (int j = 0; j < 3; j++) M[i][j] = (double)Mf[3*i+j];
    for (int i = 0; i < 3; i++)
        for (int j = 0; j < 3; j++)
            S[i][j] = M[0][i]*M[0][j] + M[1][i]*M[1][j] + M[2][i]*M[2][j];
    for (int i = 0; i < 3; i++)
        for (int j = 0; j < 3; j++) V[i][j] = (i == j) ? 1.0 : 0.0;
    for (int it = 0; it < 10; it++) {
        jrot(S, V, 0, 1); jrot(S, V, 0, 2); jrot(S, V, 1, 2);
    }
    double lam[3] = {S[0][0], S[1][1], S[2][2]};
    int i0 = 0, i1 = 1, i2 = 2, tt;
    if (lam[i0] < lam[i1]) { tt = i0; i0 = i1; i1 = tt; }
    if (lam[i0] < lam[i2]) { tt = i0; i0 = i2; i2 = tt; }
    if (lam[i1] < lam[i2]) { tt = i1; i1 = i2; i2 = tt; }
    double v0[3], v1[3], v2[3];
    for (int k = 0; k < 3; k++) { v0[k] = V[k][i0]; v1[k] = V[k][i1]; v2[k] = V[k][i2]; }
    // u1 = normalize(M v0)
    double u1[3], u2[3], u3[3];
    for (int i = 0; i < 3; i++) u1[i] = M[i][0]*v0[0] + M[i][1]*v0[1] + M[i][2]*v0[2];
    double n1 = sqrt(u1[0]*u1[0] + u1[1]*u1[1] + u1[2]*u1[2]) + 1e-300;
    for (int i = 0; i < 3; i++) u1[i] /= n1;
    // u2 = normalize(M v1 - (u1 . M v1) u1)
    for (int i = 0; i < 3; i++) u2[i] = M[i][0]*v1[0] + M[i][1]*v1[1] + M[i][2]*v1[2];
    double d12 = u1[0]*u2[0] + u1[1]*u2[1] + u1[2]*u2[2];
    for (int i = 0; i < 3; i++) u2[i] -= d12*u1[i];
    double n2 = sqrt(u2[0]*u2[0] + u2[1]*u2[1] + u2[2]*u2[2]) + 1e-300;
    for (int i = 0; i < 3; i++) u2[i] /= n2;
    // u3 = u1 x u2;  det(V) from permuted columns
    u3[0] = u1[1]*u2[2] - u1[2]*u2[1];
    u3[1] = u1[2]*u2[0] - u1[0]*u2[2];
    u3[2] = u1[0]*u2[1] - u1[1]*u2[0];
    double c12x = v1[1]*v2[2] - v1[2]*v2[1];
    double c12y = v1[2]*v2[0] - v1[0]*v2[2];
    double c12z = v1[0]*v2[1] - v1[1]*v2[0];
    double detV = v0[0]*c12x + v0[1]*c12y + v0[2]*c12z;
    // R = [u1, u2, detV * u3] V^T  ==  U diag(1,1,det(UV^T)) V^T
    for (int i = 0; i < 3; i++)
        for (int j = 0; j < 3; j++)
            Rout[3*i+j] = (float)(u1[i]*v0[j] + u2[i]*v1[j] + detV*u3[i]*v2[j]);
}

// ---------------------------------------------------------------------------
// Kernel C: head MLP (fp32) + SVD projection. 8 batches / block, 32 blocks.
// ---------------------------------------------------------------------------
__global__ __launch_bounds__(256) void head_svd(
    const float* __restrict__ g,
    const float* __restrict__ Wh1, const float* __restrict__ bh1,
    const float* __restrict__ Wh2, const float* __restrict__ bh2,
    const float* __restrict__ Wh3, const float* __restrict__ bh3,
    float* __restrict__ out)
{
    __shared__ float gs[8][1024];
    __shared__ float z1s[8][512];
    __shared__ float z2s[8][256];
    __shared__ float raws[8][12];
    int b0 = blockIdx.x * 8;
    int tid = threadIdx.x;

    for (int i = tid; i < 8*1024; i += 256) gs[i >> 10][i & 1023] = g[(size_t)b0*1024 + i];
    __syncthreads();

    // z1 = relu(g @ Wh1 + bh1): 512 cols
#pragma unroll 1
    for (int cc = 0; cc < 2; cc++) {
        int c = cc*256 + tid;
        float bb = bh1[c];
        float acc[8];
#pragma unroll
        for (int r = 0; r < 8; r++) acc[r] = bb;
        for (int k = 0; k < 1024; k++) {
            float w = Wh1[(size_t)k*512 + c];
#pragma unroll
            for (int r = 0; r < 8; r++) acc[r] = fmaf(gs[r][k], w, acc[r]);
        }
#pragma unroll
        for (int r = 0; r < 8; r++) z1s[r][c] = fmaxf(acc[r], 0.f);
    }
    __syncthreads();

    // z2 = relu(z1 @ Wh2 + bh2): 256 cols
    {
        int c = tid;
        float bb = bh2[c];
        float acc[8];
#pragma unroll
        for (int r = 0; r < 8; r++) acc[r] = bb;
        for (int k = 0; k < 512; k++) {
            float w = Wh2[(size_t)k*256 + c];
#pragma unroll
            for (int r = 0; r < 8; r++) acc[r] = fmaf(z1s[r][k], w, acc[r]);
        }
#pragma unroll
        for (int r = 0; r < 8; r++) z2s[r][c] = fmaxf(acc[r], 0.f);
    }
    __syncthreads();

    // raw = z2 @ Wh3 + bh3: 8 rows x 9 cols
    if (tid < 72) {
        int r = tid / 9, c = tid % 9;
        float acc = bh3[c];
        for (int k = 0; k < 256; k++) acc = fmaf(z2s[r][k], Wh3[k*9 + c], acc);
        raws[r][c] = acc;
    }
    __syncthreads();

    if (tid < 8) svd_so3(&raws[tid][0], out + (size_t)(b0 + tid)*9);
}

// ---------------------------------------------------------------------------
extern "C" void kernel_launch(void* const* d_in, const int* in_sizes, int n_in,
                              void* d_out, int out_size, void* d_ws, size_t ws_size,
                              hipStream_t stream)
{
    const float* x   = (const float*)d_in[0];
    const float* W1  = (const float*)d_in[1];
    const float* b1  = (const float*)d_in[2];
    const float* W2  = (const float*)d_in[3];
    const float* b2  = (const float*)d_in[4];
    const float* W3  = (const float*)d_in[5];
    const float* b3  = (const float*)d_in[6];
    const float* Wh1 = (const float*)d_in[7];
    const float* bh1 = (const float*)d_in[8];
    const float* Wh2 = (const float*)d_in[9];
    const float* bh2 = (const float*)d_in[10];
    const float* Wh3 = (const float*)d_in[11];
    const float* bh3 = (const float*)d_in[12];
    float* out = (float*)d_out;

    char* ws = (char*)d_ws;
    f16*   h2  = (f16*)ws;                                   // 64 MB
    f16*   w3t = (f16*)(ws + (size_t)67108864);              // 256 KB
    float* g   = (float*)(ws + (size_t)67108864 + 262144);   // 1 MB

    pointnet_l12<<<1024, 256, 0, stream>>>(x, W1, b1, W2, b2, h2);
    prep_w3t<<<512, 256, 0, stream>>>(W3, w3t);
    dim3 gridB(8, 256);
    pointnet_l3_max<<<gridB, 256, 0, stream>>>(h2, w3t, b3, g);
    head_svd<<<32, 256, 0, stream>>>(g, Wh1, bh1, Wh2, bh2, Wh3, bh3, out);
}

// Round 2
// 381.245 us; speedup vs baseline: 1.0349x; 1.0349x over previous
//
#include <hip/hip_runtime.h>
#include <math.h>

typedef _Float16 f16;
typedef _Float16 f16x8 __attribute__((ext_vector_type(8)));
typedef float f32x4 __attribute__((ext_vector_type(4)));

#define LDS_STRIDE 136  // 128 + 8 f16 pad -> 272B rows, 16B aligned, conflict-free b128

// ---------------------------------------------------------------------------
// Kernel A: per-point MLP layers 1-2 (fp32 compute), store h2 as f16 [pt][128]
// ---------------------------------------------------------------------------
__global__ __launch_bounds__(256) void pointnet_l12(
    const float* __restrict__ x,
    const float* __restrict__ W1, const float* __restrict__ b1,
    const float* __restrict__ W2, const float* __restrict__ b2,
    f16* __restrict__ h2)
{
    int p = blockIdx.x * 256 + threadIdx.x;  // 262144 points
    float x0 = x[3*p], x1 = x[3*p+1], x2 = x[3*p+2];
    float h1[64];
#pragma unroll
    for (int j = 0; j < 64; j++) {
        float a = fmaf(x2, W1[128+j], fmaf(x1, W1[64+j], fmaf(x0, W1[j], b1[j])));
        h1[j] = fmaxf(a, 0.f);
    }
#pragma unroll 1
    for (int c0 = 0; c0 < 128; c0 += 8) {
        float acc[8];
#pragma unroll
        for (int j = 0; j < 8; j++) acc[j] = b2[c0+j];
#pragma unroll
        for (int k = 0; k < 64; k++) {
#pragma unroll
            for (int j = 0; j < 8; j++)
                acc[j] = fmaf(h1[k], W2[k*128 + c0 + j], acc[j]);
        }
        f16x8 o;
#pragma unroll
        for (int j = 0; j < 8; j++) o[j] = (f16)fmaxf(acc[j], 0.f);
        *(f16x8*)(h2 + (size_t)p*128 + c0) = o;
    }
}

// ---------------------------------------------------------------------------
// Prep: W3 [128][1024] fp32 -> W3T f16 [1024 n][128 k]  (B-fragment layout)
// ---------------------------------------------------------------------------
__global__ void prep_w3t(const float* __restrict__ w3, f16* __restrict__ w3t)
{
    int idx = blockIdx.x * 256 + threadIdx.x;  // 131072
    int n = idx >> 7, k = idx & 127;
    w3t[idx] = (f16)w3[k*1024 + n];
}

// ---------------------------------------------------------------------------
// Kernel B: per batch, h2[1024x128] @ W3[128x1024] (f16 MFMA), relu+bias,
// max over points -> g[B][1024]. Block = (batch, 128-col tile), 4 waves 2x2.
// B-fragments (full K) live in registers for the whole kernel.
// ---------------------------------------------------------------------------
__global__ __launch_bounds__(256, 2) void pointnet_l3_max(
    const f16* __restrict__ h2,    // [B*1024][128]
    const f16* __restrict__ w3t,   // [1024][128]
    const float* __restrict__ b3,  // [1024]
    float* __restrict__ g)         // [B][1024]
{
    __shared__ __align__(16) f16 atile[128 * LDS_STRIDE];  // 34816 B
    __shared__ float redbuf[4][64];

    int nb  = blockIdx.x;          // 0..7 col block
    int b   = blockIdx.y;          // 0..255 batch
    int tid = threadIdx.x;
    int lane = tid & 63, wid = tid >> 6;
    int wr = wid & 1, wc = wid >> 1;
    int lrow = lane & 15, quad = lane >> 4;
    int col0 = nb*128 + wc*64;

    // Load B-fragments: 4 col-tiles x 4 k-chunks, 16B each (64 VGPRs)
    f16x8 bf[4][4];
#pragma unroll
    for (int ct = 0; ct < 4; ct++)
#pragma unroll
        for (int kc = 0; kc < 4; kc++)
            bf[ct][kc] = *(const f16x8*)(w3t + (size_t)(col0 + ct*16 + lrow)*128 + kc*32 + quad*8);

    float cmax[4] = {-3.0e38f, -3.0e38f, -3.0e38f, -3.0e38f};
    const f16* abase = h2 + (size_t)b * 1024 * 128;

    for (int m0 = 0; m0 < 1024; m0 += 128) {
        __syncthreads();
        // stage A m-tile: 128 rows x 128 k, f16, padded rows
#pragma unroll
        for (int i = 0; i < 8; i++) {
            int e = tid + i*256;               // 2048 chunks of 16B
            int row = e >> 4, cch = e & 15;
            *(f16x8*)(atile + row*LDS_STRIDE + cch*8) =
                *(const f16x8*)(abase + (size_t)(m0+row)*128 + cch*8);
        }
        __syncthreads();

        f32x4 acc[4][4];
#pragma unroll
        for (int rt = 0; rt < 4; rt++)
#pragma unroll
            for (int ct = 0; ct < 4; ct++)
                acc[rt][ct] = (f32x4){0.f, 0.f, 0.f, 0.f};

#pragma unroll
        for (int kc = 0; kc < 4; kc++) {
            f16x8 af[4];
#pragma unroll
            for (int rt = 0; rt < 4; rt++)
                af[rt] = *(const f16x8*)(atile + (wr*64 + rt*16 + lrow)*LDS_STRIDE + kc*32 + quad*8);
#pragma unroll
            for (int rt = 0; rt < 4; rt++)
#pragma unroll
                for (int ct = 0; ct < 4; ct++)
                    acc[rt][ct] = __builtin_amdgcn_mfma_f32_16x16x32_f16(af[rt], bf[ct][kc], acc[rt][ct], 0, 0, 0);
        }
        // fold rows into running col-max (bias+relu deferred: monotone)
#pragma unroll
        for (int rt = 0; rt < 4; rt++)
#pragma unroll
            for (int ct = 0; ct < 4; ct++)
#pragma unroll
                for (int r = 0; r < 4; r++)
                    cmax[ct] = fmaxf(cmax[ct], acc[rt][ct][r]);
    }

    // reduce across quads (rows split by quad): lanes L, L^16, L^32
#pragma unroll
    for (int ct = 0; ct < 4; ct++) {
        cmax[ct] = fmaxf(cmax[ct], __shfl_xor(cmax[ct], 16, 64));
        cmax[ct] = fmaxf(cmax[ct], __shfl_xor(cmax[ct], 32, 64));
    }
    if (quad == 0) {
#pragma unroll
        for (int ct = 0; ct < 4; ct++) redbuf[wid][ct*16 + lrow] = cmax[ct];
    }
    __syncthreads();
    if (tid < 128) {
        int c = tid;                  // col within block
        int wcc = c >> 6;
        float v = fmaxf(redbuf[wcc*2][c & 63], redbuf[wcc*2+1][c & 63]);
        int gc = nb*128 + c;
        g[(size_t)b*1024 + gc] = fmaxf(v + b3[gc], 0.f);
    }
}

// ---------------------------------------------------------------------------
// Head layer 1: z1 = relu(g @ Wh1 + bh1).  M=256,N=512,K=1024.
// Block: 8 batches x 64 cols, thread -> 2 batches. Grid (8 colblk, 32 batblk).
// ---------------------------------------------------------------------------
__global__ __launch_bounds__(256) void head_l1(
    const float* __restrict__ g, const float* __restrict__ Wh1,
    const float* __restrict__ bh1, float* __restrict__ z1)
{
    __shared__ float gs[8][1024];
    int cb = blockIdx.x;          // 0..7
    int bb = blockIdx.y;          // 0..31
    int tid = threadIdx.x;
    int b0 = bb * 8;
    for (int i = tid; i < 8*1024; i += 256)
        gs[i >> 10][i & 1023] = g[(size_t)b0*1024 + i];
    __syncthreads();

    int c  = cb*64 + (tid & 63);
    int r0 = (tid >> 6) * 2;      // batch pair within the 8
    float acc0 = bh1[c], acc1 = acc0;
#pragma unroll 1
    for (int k = 0; k < 1024; k += 4) {
        float w0 = Wh1[(size_t)(k  )*512 + c];
        float w1 = Wh1[(size_t)(k+1)*512 + c];
        float w2 = Wh1[(size_t)(k+2)*512 + c];
        float w3 = Wh1[(size_t)(k+3)*512 + c];
        acc0 = fmaf(gs[r0  ][k  ], w0, acc0);
        acc1 = fmaf(gs[r0+1][k  ], w0, acc1);
        acc0 = fmaf(gs[r0  ][k+1], w1, acc0);
        acc1 = fmaf(gs[r0+1][k+1], w1, acc1);
        acc0 = fmaf(gs[r0  ][k+2], w2, acc0);
        acc1 = fmaf(gs[r0+1][k+2], w2, acc1);
        acc0 = fmaf(gs[r0  ][k+3], w3, acc0);
        acc1 = fmaf(gs[r0+1][k+3], w3, acc1);
    }
    z1[(size_t)(b0+r0  )*512 + c] = fmaxf(acc0, 0.f);
    z1[(size_t)(b0+r0+1)*512 + c] = fmaxf(acc1, 0.f);
}

// ---------------------------------------------------------------------------
// Head layer 2: z2 = relu(z1 @ Wh2 + bh2).  M=256,N=256,K=512.
// Block: 8 batches x 64 cols. Grid (4 colblk, 32 batblk).
// ---------------------------------------------------------------------------
__global__ __launch_bounds__(256) void head_l2(
    const float* __restrict__ z1, const float* __restrict__ Wh2,
    const float* __restrict__ bh2, float* __restrict__ z2)
{
    __shared__ float z1s[8][512];
    int cb = blockIdx.x;          // 0..3
    int bb = blockIdx.y;          // 0..31
    int tid = threadIdx.x;
    int b0 = bb * 8;
    for (int i = tid; i < 8*512; i += 256)
        z1s[i >> 9][i & 511] = z1[(size_t)b0*512 + i];
    __syncthreads();

    int c  = cb*64 + (tid & 63);
    int r0 = (tid >> 6) * 2;
    float acc0 = bh2[c], acc1 = acc0;
#pragma unroll 1
    for (int k = 0; k < 512; k += 4) {
        float w0 = Wh2[(size_t)(k  )*256 + c];
        float w1 = Wh2[(size_t)(k+1)*256 + c];
        float w2 = Wh2[(size_t)(k+2)*256 + c];
        float w3 = Wh2[(size_t)(k+3)*256 + c];
        acc0 = fmaf(z1s[r0  ][k  ], w0, acc0);
        acc1 = fmaf(z1s[r0+1][k  ], w0, acc1);
        acc0 = fmaf(z1s[r0  ][k+1], w1, acc0);
        acc1 = fmaf(z1s[r0+1][k+1], w1, acc1);
        acc0 = fmaf(z1s[r0  ][k+2], w2, acc0);
        acc1 = fmaf(z1s[r0+1][k+2], w2, acc1);
        acc0 = fmaf(z1s[r0  ][k+3], w3, acc0);
        acc1 = fmaf(z1s[r0+1][k+3], w3, acc1);
    }
    z2[(size_t)(b0+r0  )*256 + c] = fmaxf(acc0, 0.f);
    z2[(size_t)(b0+r0+1)*256 + c] = fmaxf(acc1, 0.f);
}

// ---------------------------------------------------------------------------
// SVD -> SO(3) projection, fp64 Jacobi on M^T M (per-thread serial)
// ---------------------------------------------------------------------------
__device__ inline void jrot(double S[3][3], double V[3][3], int p, int q)
{
    double apq = S[p][q];
    if (fabs(apq) < 1e-36) return;
    double tau = (S[q][q] - S[p][p]) / (2.0 * apq);
    double t = (tau >= 0.0 ? 1.0 : -1.0) / (fabs(tau) + sqrt(1.0 + tau*tau));
    double c = 1.0 / sqrt(1.0 + t*t);
    double s = t * c;
    for (int k = 0; k < 3; k++) {
        double skp = S[k][p], skq = S[k][q];
        S[k][p] = c*skp - s*skq;  S[k][q] = s*skp + c*skq;
    }
    for (int k = 0; k < 3; k++) {
        double spk = S[p][k], sqk = S[q][k];
        S[p][k] = c*spk - s*sqk;  S[q][k] = s*spk + c*sqk;
    }
    for (int k = 0; k < 3; k++) {
        double vkp = V[k][p], vkq = V[k][q];
        V[k][p] = c*vkp - s*vkq;  V[k][q] = s*vkp + c*vkq;
    }
}

__device__ void svd_so3(const float* Mf, float* Rout)
{
    double M[3][3], S[3][3], V[3][3];
    for (int i = 0; i < 3; i++)
        for (int j = 0; j < 3; j++) M[i][j] = (double)Mf[3*i+j];
    for (int i = 0; i < 3; i++)
        for (int j = 0; j < 3; j++)
            S[i][j] = M[0][i]*M[0][j] + M[1][i]*M[1][j] + M[2][i]*M[2][j];
    for (int i = 0; i < 3; i++)
        for (int j = 0; j < 3; j++) V[i][j] = (i == j) ? 1.0 : 0.0;
    for (int it = 0; it < 10; it++) {
        jrot(S, V, 0, 1); jrot(S, V, 0, 2); jrot(S, V, 1, 2);
    }
    double lam[3] = {S[0][0], S[1][1], S[2][2]};
    int i0 = 0, i1 = 1, i2 = 2, tt;
    if (lam[i0] < lam[i1]) { tt = i0; i0 = i1; i1 = tt; }
    if (lam[i0] < lam[i2]) { tt = i0; i0 = i2; i2 = tt; }
    if (lam[i1] < lam[i2]) { tt = i1; i1 = i2; i2 = tt; }
    double v0[3], v1[3], v2[3];
    for (int k = 0; k < 3; k++) { v0[k] = V[k][i0]; v1[k] = V[k][i1]; v2[k] = V[k][i2]; }
    double u1[3], u2[3], u3[3];
    for (int i = 0; i < 3; i++) u1[i] = M[i][0]*v0[0] + M[i][1]*v0[1] + M[i][2]*v0[2];
    double n1 = sqrt(u1[0]*u1[0] + u1[1]*u1[1] + u1[2]*u1[2]) + 1e-300;
    for (int i = 0; i < 3; i++) u1[i] /= n1;
    for (int i = 0; i < 3; i++) u2[i] = M[i][0]*v1[0] + M[i][1]*v1[1] + M[i][2]*v1[2];
    double d12 = u1[0]*u2[0] + u1[1]*u2[1] + u1[2]*u2[2];
    for (int i = 0; i < 3; i++) u2[i] -= d12*u1[i];
    double n2 = sqrt(u2[0]*u2[0] + u2[1]*u2[1] + u2[2]*u2[2]) + 1e-300;
    for (int i = 0; i < 3; i++) u2[i] /= n2;
    u3[0] = u1[1]*u2[2] - u1[2]*u2[1];
    u3[1] = u1[2]*u2[0] - u1[0]*u2[2];
    u3[2] = u1[0]*u2[1] - u1[1]*u2[0];
    double c12x = v1[1]*v2[2] - v1[2]*v2[1];
    double c12y = v1[2]*v2[0] - v1[0]*v2[2];
    double c12z = v1[0]*v2[1] - v1[1]*v2[0];
    double detV = v0[0]*c12x + v0[1]*c12y + v0[2]*c12z;
    for (int i = 0; i < 3; i++)
        for (int j = 0; j < 3; j++)
            Rout[3*i+j] = (float)(u1[i]*v0[j] + u2[i]*v1[j] + detV*u3[i]*v2[j]);
}

// ---------------------------------------------------------------------------
// Head tail: raw = z2 @ Wh3 + bh3, then SVD->SO(3). 8 batches/block, 32 blocks.
// ---------------------------------------------------------------------------
__global__ __launch_bounds__(128) void head_l3_svd(
    const float* __restrict__ z2,
    const float* __restrict__ Wh3, const float* __restrict__ bh3,
    float* __restrict__ out)
{
    __shared__ float z2s[8][256];
    __shared__ float raws[8][12];
    int b0 = blockIdx.x * 8;
    int tid = threadIdx.x;

    for (int i = tid; i < 8*256; i += 128)
        z2s[i >> 8][i & 255] = z2[(size_t)b0*256 + i];
    __syncthreads();

    if (tid < 72) {
        int r = tid / 9, c = tid % 9;
        float acc = bh3[c];
#pragma unroll 4
        for (int k = 0; k < 256; k++) acc = fmaf(z2s[r][k], Wh3[k*9 + c], acc);
        raws[r][c] = acc;
    }
    __syncthreads();

    if (tid < 8) svd_so3(&raws[tid][0], out + (size_t)(b0 + tid)*9);
}

// ---------------------------------------------------------------------------
extern "C" void kernel_launch(void* const* d_in, const int* in_sizes, int n_in,
                              void* d_out, int out_size, void* d_ws, size_t ws_size,
                              hipStream_t stream)
{
    const float* x   = (const float*)d_in[0];
    const float* W1  = (const float*)d_in[1];
    const float* b1  = (const float*)d_in[2];
    const float* W2  = (const float*)d_in[3];
    const float* b2  = (const float*)d_in[4];
    const float* W3  = (const float*)d_in[5];
    const float* b3  = (const float*)d_in[6];
    const float* Wh1 = (const float*)d_in[7];
    const float* bh1 = (const float*)d_in[8];
    const float* Wh2 = (const float*)d_in[9];
    const float* bh2 = (const float*)d_in[10];
    const float* Wh3 = (const float*)d_in[11];
    const float* bh3 = (const float*)d_in[12];
    float* out = (float*)d_out;

    char* ws = (char*)d_ws;
    f16*   h2  = (f16*)ws;                                     // 64 MB
    f16*   w3t = (f16*)(ws + (size_t)67108864);                // 256 KB
    float* g   = (float*)(ws + (size_t)67108864 + 262144);     // 1 MB
    float* z1  = (float*)(ws + (size_t)67108864 + 262144 + 1048576);            // 512 KB
    float* z2  = (float*)(ws + (size_t)67108864 + 262144 + 1048576 + 524288);   // 256 KB

    pointnet_l12<<<1024, 256, 0, stream>>>(x, W1, b1, W2, b2, h2);
    prep_w3t<<<512, 256, 0, stream>>>(W3, w3t);
    dim3 gridB(8, 256);
    pointnet_l3_max<<<gridB, 256, 0, stream>>>(h2, w3t, b3, g);
    dim3 gridH1(8, 32);
    head_l1<<<gridH1, 256, 0, stream>>>(g, Wh1, bh1, z1);
    dim3 gridH2(4, 32);
    head_l2<<<gridH2, 256, 0, stream>>>(z1, Wh2, bh2, z2);
    head_l3_svd<<<32, 128, 0, stream>>>(z2, Wh3, bh3, out);
}

// Round 3
// 287.064 us; speedup vs baseline: 1.3744x; 1.3281x over previous
//
#include <hip/hip_runtime.h>
#include <math.h>

typedef _Float16 f16;
typedef _Float16 f16x8 __attribute__((ext_vector_type(8)));
typedef float f32x4 __attribute__((ext_vector_type(4)));

// async global->LDS, 16B per lane. LDS dest = wave-uniform base + lane*16.
__device__ __forceinline__ void glds16(const void* g, void* l) {
    __builtin_amdgcn_global_load_lds(
        (const __attribute__((address_space(1))) unsigned int*)g,
        (__attribute__((address_space(3))) unsigned int*)l, 16, 0, 0);
}

// ---------------------------------------------------------------------------
// Kernel A: per-point MLP layers 1-2 (fp32), store h2 f16 [pt][128] with the
// 16B-chunk index XOR-swizzled by (pt&15) so kernel B can global_load_lds a
// contiguous tile and still ds_read_b128 conflict-free.
// ---------------------------------------------------------------------------
__global__ __launch_bounds__(256) void pointnet_l12(
    const float* __restrict__ x,
    const float* __restrict__ W1, const float* __restrict__ b1,
    const float* __restrict__ W2, const float* __restrict__ b2,
    f16* __restrict__ h2)
{
    int p = blockIdx.x * 256 + threadIdx.x;  // 262144 points
    float x0 = x[3*p], x1 = x[3*p+1], x2 = x[3*p+2];
    float h1[64];
#pragma unroll
    for (int j = 0; j < 64; j++) {
        float a = fmaf(x2, W1[128+j], fmaf(x1, W1[64+j], fmaf(x0, W1[j], b1[j])));
        h1[j] = fmaxf(a, 0.f);
    }
    int sw = p & 15;
#pragma unroll 1
    for (int c0 = 0; c0 < 128; c0 += 8) {
        float acc[8];
#pragma unroll
        for (int j = 0; j < 8; j++) acc[j] = b2[c0+j];
#pragma unroll
        for (int k = 0; k < 64; k++) {
#pragma unroll
            for (int j = 0; j < 8; j++)
                acc[j] = fmaf(h1[k], W2[k*128 + c0 + j], acc[j]);
        }
        f16x8 o;
#pragma unroll
        for (int j = 0; j < 8; j++) o[j] = (f16)fmaxf(acc[j], 0.f);
        int slot = (c0 >> 3) ^ sw;               // swizzled 16B-chunk slot
        *(f16x8*)(h2 + (size_t)p*128 + slot*8) = o;
    }
}

// ---------------------------------------------------------------------------
// Prep: W3 [128][1024] fp32 -> W3T f16 [1024 n][128 k]  (B-fragment layout)
// ---------------------------------------------------------------------------
__global__ void prep_w3t(const float* __restrict__ w3, f16* __restrict__ w3t)
{
    int idx = blockIdx.x * 256 + threadIdx.x;  // 131072
    int n = idx >> 7, k = idx & 127;
    w3t[idx] = (f16)w3[k*1024 + n];
}

// ---------------------------------------------------------------------------
// Kernel B: per batch, h2[1024x128] @ W3[128x1024] (f16 MFMA), bias+relu+max
// over points -> g[B][1024]. Block=(col128, batch), 4 waves 2x2.
// A staged via global_load_lds (contiguous 32KB copy; data pre-swizzled).
// ---------------------------------------------------------------------------
__global__ __launch_bounds__(256, 2) void pointnet_l3_max(
    const f16* __restrict__ h2,    // [B*1024][128] swizzled chunks
    const f16* __restrict__ w3t,   // [1024][128]
    const float* __restrict__ b3,  // [1024]
    float* __restrict__ g)         // [B][1024]
{
    __shared__ __align__(16) f16 atile[128 * 128];  // 32 KB, unpadded
    __shared__ float redbuf[4][64];

    int nb  = blockIdx.x;          // 0..7 col block
    int b   = blockIdx.y;          // 0..255 batch
    int tid = threadIdx.x;
    int lane = tid & 63, wid = tid >> 6;
    int wr = wid & 1, wc = wid >> 1;
    int lrow = lane & 15, quad = lane >> 4;
    int col0 = nb*128 + wc*64;

    // B-fragments: 4 col-tiles x 4 k-chunks, 16B each (64 VGPRs), whole K
    f16x8 bf[4][4];
#pragma unroll
    for (int ct = 0; ct < 4; ct++)
#pragma unroll
        for (int kc = 0; kc < 4; kc++)
            bf[ct][kc] = *(const f16x8*)(w3t + (size_t)(col0 + ct*16 + lrow)*128 + kc*32 + quad*8);

    float cmax[4] = {-3.0e38f, -3.0e38f, -3.0e38f, -3.0e38f};
    const f16* abase = h2 + (size_t)b * 1024 * 128;

    for (int m0 = 0; m0 < 1024; m0 += 128) {
        __syncthreads();
        // stage A m-tile: straight 32KB copy, wave w covers chunks [w*512, w*512+512)
        {
            const f16* gsrc = abase + (size_t)m0 * 128;
#pragma unroll
            for (int i = 0; i < 8; i++) {
                int chunk = wid*512 + i*64 + lane;
                glds16(gsrc + chunk*8, atile + (wid*512 + i*64)*8);
            }
        }
        __syncthreads();

        f32x4 acc[4][4];
#pragma unroll
        for (int rt = 0; rt < 4; rt++)
#pragma unroll
            for (int ct = 0; ct < 4; ct++)
                acc[rt][ct] = (f32x4){0.f, 0.f, 0.f, 0.f};

#pragma unroll
        for (int kc = 0; kc < 4; kc++) {
            f16x8 af[4];
#pragma unroll
            for (int rt = 0; rt < 4; rt++) {
                int row  = wr*64 + rt*16 + lrow;
                int slot = (kc*4 + quad) ^ lrow;   // un-swizzle
                af[rt] = *(const f16x8*)(atile + row*128 + slot*8);
            }
#pragma unroll
            for (int rt = 0; rt < 4; rt++)
#pragma unroll
                for (int ct = 0; ct < 4; ct++)
                    acc[rt][ct] = __builtin_amdgcn_mfma_f32_16x16x32_f16(af[rt], bf[ct][kc], acc[rt][ct], 0, 0, 0);
        }
#pragma unroll
        for (int rt = 0; rt < 4; rt++)
#pragma unroll
            for (int ct = 0; ct < 4; ct++)
#pragma unroll
                for (int r = 0; r < 4; r++)
                    cmax[ct] = fmaxf(cmax[ct], acc[rt][ct][r]);
    }

#pragma unroll
    for (int ct = 0; ct < 4; ct++) {
        cmax[ct] = fmaxf(cmax[ct], __shfl_xor(cmax[ct], 16, 64));
        cmax[ct] = fmaxf(cmax[ct], __shfl_xor(cmax[ct], 32, 64));
    }
    if (quad == 0) {
#pragma unroll
        for (int ct = 0; ct < 4; ct++) redbuf[wid][ct*16 + lrow] = cmax[ct];
    }
    __syncthreads();
    if (tid < 128) {
        int c = tid;
        int wcc = c >> 6;
        float v = fmaxf(redbuf[wcc*2][c & 63], redbuf[wcc*2+1][c & 63]);
        int gc = nb*128 + c;
        g[(size_t)b*1024 + gc] = fmaxf(v + b3[gc], 0.f);
    }
}

// ---------------------------------------------------------------------------
// Head layer 1 partials: zp1[kc][b][c] = sum_{k in chunk} g[b][k]*Wh1[k][c].
// Grid (cb=2, bb=64, kc=4) = 512 blocks; block 256 thr; 4 batches/block.
// ---------------------------------------------------------------------------
__global__ __launch_bounds__(256) void head_l1(
    const float* __restrict__ g, const float* __restrict__ Wh1,
    float* __restrict__ zp1)
{
    __shared__ float gs4[4][256];
    int cb = blockIdx.x, bb = blockIdx.y, kc = blockIdx.z;
    int tid = threadIdx.x;
    int b0 = bb * 4;
    int kbase = kc * 256;
#pragma unroll
    for (int j = 0; j < 4; j++) {
        int i = tid + j*256;
        gs4[i >> 8][i & 255] = g[(size_t)(b0 + (i >> 8))*1024 + kbase + (i & 255)];
    }
    __syncthreads();

    int c = cb*256 + tid;
    float acc[4] = {0.f, 0.f, 0.f, 0.f};
#pragma unroll 1
    for (int k = 0; k < 256; k += 8) {
        float w[8];
#pragma unroll
        for (int j = 0; j < 8; j++) w[j] = Wh1[(size_t)(kbase+k+j)*512 + c];
#pragma unroll
        for (int r = 0; r < 4; r++) {
            float4 a = *(const float4*)&gs4[r][k];
            float4 bq = *(const float4*)&gs4[r][k+4];
            acc[r] = fmaf(a.x, w[0], acc[r]);
            acc[r] = fmaf(a.y, w[1], acc[r]);
            acc[r] = fmaf(a.z, w[2], acc[r]);
            acc[r] = fmaf(a.w, w[3], acc[r]);
            acc[r] = fmaf(bq.x, w[4], acc[r]);
            acc[r] = fmaf(bq.y, w[5], acc[r]);
            acc[r] = fmaf(bq.z, w[6], acc[r]);
            acc[r] = fmaf(bq.w, w[7], acc[r]);
        }
    }
#pragma unroll
    for (int r = 0; r < 4; r++)
        zp1[((size_t)kc*256 + b0 + r)*512 + c] = acc[r];
}

// ---------------------------------------------------------------------------
// Head layer 2 partials, z1-reduce fused into staging.
// Grid (bb=128, kc2=4) = 512 blocks; block 256; 2 batches/block, all 256 cols.
// ---------------------------------------------------------------------------
__global__ __launch_bounds__(256) void head_l2(
    const float* __restrict__ zp1, const float* __restrict__ bh1,
    const float* __restrict__ Wh2, float* __restrict__ zp2)
{
    __shared__ float z1s[2][128];
    int bb = blockIdx.x, kc2 = blockIdx.y;
    int tid = threadIdx.x;
    int b0 = bb * 2;
    int kb = kc2 * 128;
    {
        int row = tid >> 7, kk = tid & 127;
        int col = kb + kk;
        float v = bh1[col];
#pragma unroll
        for (int j = 0; j < 4; j++)
            v += zp1[((size_t)j*256 + b0 + row)*512 + col];
        z1s[row][kk] = fmaxf(v, 0.f);
    }
    __syncthreads();

    int c = tid;
    float acc0 = 0.f, acc1 = 0.f;
#pragma unroll 1
    for (int k = 0; k < 128; k += 8) {
        float w[8];
#pragma unroll
        for (int j = 0; j < 8; j++) w[j] = Wh2[(size_t)(kb+k+j)*256 + c];
        float4 a0 = *(const float4*)&z1s[0][k];
        float4 a1 = *(const float4*)&z1s[0][k+4];
        float4 d0 = *(const float4*)&z1s[1][k];
        float4 d1 = *(const float4*)&z1s[1][k+4];
        acc0 = fmaf(a0.x, w[0], acc0);  acc1 = fmaf(d0.x, w[0], acc1);
        acc0 = fmaf(a0.y, w[1], acc0);  acc1 = fmaf(d0.y, w[1], acc1);
        acc0 = fmaf(a0.z, w[2], acc0);  acc1 = fmaf(d0.z, w[2], acc1);
        acc0 = fmaf(a0.w, w[3], acc0);  acc1 = fmaf(d0.w, w[3], acc1);
        acc0 = fmaf(a1.x, w[4], acc0);  acc1 = fmaf(d1.x, w[4], acc1);
        acc0 = fmaf(a1.y, w[5], acc0);  acc1 = fmaf(d1.y, w[5], acc1);
        acc0 = fmaf(a1.z, w[6], acc0);  acc1 = fmaf(d1.z, w[6], acc1);
        acc0 = fmaf(a1.w, w[7], acc0);  acc1 = fmaf(d1.w, w[7], acc1);
    }
    zp2[((size_t)kc2*256 + b0    )*256 + c] = acc0;
    zp2[((size_t)kc2*256 + b0 + 1)*256 + c] = acc1;
}

// ---------------------------------------------------------------------------
// SVD -> SO(3) projection, fp64 Jacobi on M^T M (per-thread serial)
// ---------------------------------------------------------------------------
__device__ inline void jrot(double S[3][3], double V[3][3], int p, int q)
{
    double apq = S[p][q];
    if (fabs(apq) < 1e-36) return;
    double tau = (S[q][q] - S[p][p]) / (2.0 * apq);
    double t = (tau >= 0.0 ? 1.0 : -1.0) / (fabs(tau) + sqrt(1.0 + tau*tau));
    double c = 1.0 / sqrt(1.0 + t*t);
    double s = t * c;
    for (int k = 0; k < 3; k++) {
        double skp = S[k][p], skq = S[k][q];
        S[k][p] = c*skp - s*skq;  S[k][q] = s*skp + c*skq;
    }
    for (int k = 0; k < 3; k++) {
        double spk = S[p][k], sqk = S[q][k];
        S[p][k] = c*spk - s*sqk;  S[q][k] = s*spk + c*sqk;
    }
    for (int k = 0; k < 3; k++) {
        double vkp = V[k][p], vkq = V[k][q];
        V[k][p] = c*vkp - s*vkq;  V[k][q] = s*vkp + c*vkq;
    }
}

__device__ void svd_so3(const float* Mf, float* Rout)
{
    double M[3][3], S[3][3], V[3][3];
    for (int i = 0; i < 3; i++)
        for (int j = 0; j < 3; j++) M[i][j] = (double)Mf[3*i+j];
    for (int i = 0; i < 3; i++)
        for (int j = 0; j < 3; j++)
            S[i][j] = M[0][i]*M[0][j] + M[1][i]*M[1][j] + M[2][i]*M[2][j];
    for (int i = 0; i < 3; i++)
        for (int j = 0; j < 3; j++) V[i][j] = (i == j) ? 1.0 : 0.0;
    for (int it = 0; it < 10; it++) {
        jrot(S, V, 0, 1); jrot(S, V, 0, 2); jrot(S, V, 1, 2);
    }
    double lam[3] = {S[0][0], S[1][1], S[2][2]};
    int i0 = 0, i1 = 1, i2 = 2, tt;
    if (lam[i0] < lam[i1]) { tt = i0; i0 = i1; i1 = tt; }
    if (lam[i0] < lam[i2]) { tt = i0; i0 = i2; i2 = tt; }
    if (lam[i1] < lam[i2]) { tt = i1; i1 = i2; i2 = tt; }
    double v0[3], v1[3], v2[3];
    for (int k = 0; k < 3; k++) { v0[k] = V[k][i0]; v1[k] = V[k][i1]; v2[k] = V[k][i2]; }
    double u1[3], u2[3], u3[3];
    for (int i = 0; i < 3; i++) u1[i] = M[i][0]*v0[0] + M[i][1]*v0[1] + M[i][2]*v0[2];
    double n1 = sqrt(u1[0]*u1[0] + u1[1]*u1[1] + u1[2]*u1[2]) + 1e-300;
    for (int i = 0; i < 3; i++) u1[i] /= n1;
    for (int i = 0; i < 3; i++) u2[i] = M[i][0]*v1[0] + M[i][1]*v1[1] + M[i][2]*v1[2];
    double d12 = u1[0]*u2[0] + u1[1]*u2[1] + u1[2]*u2[2];
    for (int i = 0; i < 3; i++) u2[i] -= d12*u1[i];
    double n2 = sqrt(u2[0]*u2[0] + u2[1]*u2[1] + u2[2]*u2[2]) + 1e-300;
    for (int i = 0; i < 3; i++) u2[i] /= n2;
    u3[0] = u1[1]*u2[2] - u1[2]*u2[1];
    u3[1] = u1[2]*u2[0] - u1[0]*u2[2];
    u3[2] = u1[0]*u2[1] - u1[1]*u2[0];
    double c12x = v1[1]*v2[2] - v1[2]*v2[1];
    double c12y = v1[2]*v2[0] - v1[0]*v2[2];
    double c12z = v1[0]*v2[1] - v1[1]*v2[0];
    double detV = v0[0]*c12x + v0[1]*c12y + v0[2]*c12z;
    for (int i = 0; i < 3; i++)
        for (int j = 0; j < 3; j++)
            Rout[3*i+j] = (float)(u1[i]*v0[j] + u2[i]*v1[j] + detV*u3[i]*v2[j]);
}

// ---------------------------------------------------------------------------
// Head tail: z2-reduce + (z2 @ Wh3 + bh3) + SVD. Wh3 staged in LDS.
// 8 batches/block, 32 blocks x 128 threads.
// ---------------------------------------------------------------------------
__global__ __launch_bounds__(128) void head_l3_svd(
    const float* __restrict__ zp2, const float* __restrict__ bh2,
    const float* __restrict__ Wh3, const float* __restrict__ bh3,
    float* __restrict__ out)
{
    __shared__ float z2s[8][256];
    __shared__ float wh3s[2304];
    __shared__ float raws[8][12];
    int b0 = blockIdx.x * 8;
    int tid = threadIdx.x;

    for (int i = tid; i < 2304; i += 128) wh3s[i] = Wh3[i];
    for (int i = tid; i < 8*256; i += 128) {
        int row = i >> 8, kk = i & 255;
        float v = bh2[kk];
#pragma unroll
        for (int j = 0; j < 4; j++)
            v += zp2[((size_t)j*256 + b0 + row)*256 + kk];
        z2s[row][kk] = fmaxf(v, 0.f);
    }
    __syncthreads();

    if (tid < 72) {
        int r = tid / 9, c = tid % 9;
        float acc = bh3[c];
#pragma unroll 8
        for (int k = 0; k < 256; k++) acc = fmaf(z2s[r][k], wh3s[k*9 + c], acc);
        raws[r][c] = acc;
    }
    __syncthreads();

    if (tid < 8) svd_so3(&raws[tid][0], out + (size_t)(b0 + tid)*9);
}

// ---------------------------------------------------------------------------
extern "C" void kernel_launch(void* const* d_in, const int* in_sizes, int n_in,
                              void* d_out, int out_size, void* d_ws, size_t ws_size,
                              hipStream_t stream)
{
    const float* x   = (const float*)d_in[0];
    const float* W1  = (const float*)d_in[1];
    const float* b1  = (const float*)d_in[2];
    const float* W2  = (const float*)d_in[3];
    const float* b2  = (const float*)d_in[4];
    const float* W3  = (const float*)d_in[5];
    const float* b3  = (const float*)d_in[6];
    const float* Wh1 = (const float*)d_in[7];
    const float* bh1 = (const float*)d_in[8];
    const float* Wh2 = (const float*)d_in[9];
    const float* bh2 = (const float*)d_in[10];
    const float* Wh3 = (const float*)d_in[11];
    const float* bh3 = (const float*)d_in[12];
    float* out = (float*)d_out;

    char* ws = (char*)d_ws;
    f16*   h2  = (f16*)ws;                                 // 64 MB
    f16*   w3t = (f16*)(ws + (size_t)67108864);            // 256 KB
    float* g   = (float*)(ws + 67108864 + 262144);         // 1 MB
    float* zp1 = (float*)(ws + 67108864 + 262144 + 1048576);            // 2 MB
    float* zp2 = (float*)(ws + 67108864 + 262144 + 1048576 + 2097152);  // 1 MB

    pointnet_l12<<<1024, 256, 0, stream>>>(x, W1, b1, W2, b2, h2);
    prep_w3t<<<512, 256, 0, stream>>>(W3, w3t);
    dim3 gridB(8, 256);
    pointnet_l3_max<<<gridB, 256, 0, stream>>>(h2, w3t, b3, g);
    dim3 gridH1(2, 64, 4);
    head_l1<<<gridH1, 256, 0, stream>>>(g, Wh1, zp1);
    dim3 gridH2(128, 4);
    head_l2<<<gridH2, 256, 0, stream>>>(zp1, bh1, Wh2, zp2);
    head_l3_svd<<<32, 128, 0, stream>>>(zp2, bh2, Wh3, bh3, out);
}

// Round 4
// 191.454 us; speedup vs baseline: 2.0608x; 1.4994x over previous
//
#include <hip/hip_runtime.h>
#include <math.h>

typedef _Float16 f16;
typedef _Float16 f16x8 __attribute__((ext_vector_type(8)));
typedef float f32x4 __attribute__((ext_vector_type(4)));

// async global->LDS, 16B per lane. LDS dest = wave-uniform base + lane*16.
__device__ __forceinline__ void glds16(const void* g, void* l) {
    __builtin_amdgcn_global_load_lds(
        (const __attribute__((address_space(1))) unsigned int*)g,
        (__attribute__((address_space(3))) unsigned int*)l, 16, 0, 0);
}

// ---------------------------------------------------------------------------
// Prep: W3 [128][1024] -> w3t f16 [1024 n][128 k];  W2 [64][128] -> w2t f16
// [128 n][64 k].  LDS 64x65 tile transpose, coalesced both sides.
// Blocks 0..31: w3t (16 n-tiles x 2 k-tiles). Blocks 32..33: w2t.
// ---------------------------------------------------------------------------
__global__ __launch_bounds__(256) void prep_wt(
    const float* __restrict__ w3, const float* __restrict__ w2,
    f16* __restrict__ w3t, f16* __restrict__ w2t)
{
    __shared__ float t[64][65];
    int bid = blockIdx.x;
    int tid = threadIdx.x;
    if (bid < 32) {
        int kt = bid & 1, nt = bid >> 1;
        int k0 = kt*64, n0 = nt*64;
#pragma unroll
        for (int j = 0; j < 16; j++) {
            int r = j*4 + (tid >> 6), c = tid & 63;
            t[r][c] = w3[(size_t)(k0+r)*1024 + n0 + c];
        }
        __syncthreads();
#pragma unroll
        for (int j = 0; j < 16; j++) {
            int n = j*4 + (tid >> 6), k = tid & 63;
            w3t[(size_t)(n0+n)*128 + k0 + k] = (f16)t[k][n];
        }
    } else {
        int n0 = (bid - 32) * 64;
#pragma unroll
        for (int j = 0; j < 16; j++) {
            int r = j*4 + (tid >> 6), c = tid & 63;
            t[r][c] = w2[(size_t)r*128 + n0 + c];
        }
        __syncthreads();
#pragma unroll
        for (int j = 0; j < 16; j++) {
            int n = j*4 + (tid >> 6), k = tid & 63;
            w2t[(size_t)(n0+n)*64 + k] = (f16)t[k][n];
        }
    }
}

// ---------------------------------------------------------------------------
// Kernel A (MFMA): per-point MLP layers 1-2.  Block = 512 points (4 m-tiles
// of 128).  h1 fragments built in-register (VALU, tiny FLOP), layer2 via
// f16 MFMA with W2 B-fragments resident.  Epilogue: bias+relu+cvt, LDS
// transpose (C-layout -> row chunks), burst store with chunk^row swizzle so
// kernel B can global_load_lds contiguously.  Full rows written back-to-back
// -> no partial-line write amplification.
// ---------------------------------------------------------------------------
__global__ __launch_bounds__(256, 2) void pointnet_l12(
    const float* __restrict__ x,
    const float* __restrict__ W1, const float* __restrict__ b1,
    const f16* __restrict__ w2t, const float* __restrict__ b2,
    f16* __restrict__ h2)
{
    __shared__ float xs[512*3];                    // 6 KB
    __shared__ float w1s[192], b1s[64], b2s[128];  // 1.5 KB
    __shared__ __align__(16) f16 h2s[128*136];     // 34.8 KB, +8 pad per row

    int tid = threadIdx.x;
    int P0 = blockIdx.x * 512;
    for (int i = tid; i < 1536; i += 256) xs[i] = x[(size_t)P0*3 + i];
    if (tid < 192) w1s[tid] = W1[tid];
    else b1s[tid - 192] = b1[tid - 192];
    if (tid < 128) b2s[tid] = b2[tid];

    int lane = tid & 63, wid = tid >> 6;
    int wr = wid & 1, wc = wid >> 1;
    int lrow = lane & 15, quad = lane >> 4;

    // B-fragments: cols wc*64+ct*16+lrow, k = kc*32+quad*8 .. +8 (32 VGPR)
    f16x8 bf[4][2];
#pragma unroll
    for (int ct = 0; ct < 4; ct++)
#pragma unroll
        for (int kc = 0; kc < 2; kc++)
            bf[ct][kc] = *(const f16x8*)(w2t + (size_t)(wc*64 + ct*16 + lrow)*64 + kc*32 + quad*8);

    __syncthreads();

    for (int mt = 0; mt < 4; mt++) {
        f32x4 acc[4][4];
#pragma unroll
        for (int rt = 0; rt < 4; rt++)
#pragma unroll
            for (int ct = 0; ct < 4; ct++)
                acc[rt][ct] = (f32x4){0.f, 0.f, 0.f, 0.f};

#pragma unroll
        for (int kc = 0; kc < 2; kc++) {
            float wa[8], wb[8], wcv[8], bv[8];
#pragma unroll
            for (int j = 0; j < 8; j++) {
                int k = kc*32 + quad*8 + j;
                wa[j] = w1s[k]; wb[j] = w1s[64+k]; wcv[j] = w1s[128+k]; bv[j] = b1s[k];
            }
            f16x8 af[4];
#pragma unroll
            for (int rt = 0; rt < 4; rt++) {
                int p = mt*128 + wr*64 + rt*16 + lrow;
                float x0 = xs[p*3], x1 = xs[p*3+1], x2 = xs[p*3+2];
#pragma unroll
                for (int j = 0; j < 8; j++) {
                    float v = fmaf(x2, wcv[j], fmaf(x1, wb[j], fmaf(x0, wa[j], bv[j])));
                    af[rt][j] = (f16)fmaxf(v, 0.f);
                }
            }
#pragma unroll
            for (int rt = 0; rt < 4; rt++)
#pragma unroll
                for (int ct = 0; ct < 4; ct++)
                    acc[rt][ct] = __builtin_amdgcn_mfma_f32_16x16x32_f16(af[rt], bf[ct][kc], acc[rt][ct], 0, 0, 0);
        }

        __syncthreads();   // previous tile's h2s readers done
        // epilogue: bias+relu+cvt, scatter C-layout into h2s
#pragma unroll
        for (int rt = 0; rt < 4; rt++)
#pragma unroll
            for (int ct = 0; ct < 4; ct++) {
                int col  = wc*64 + ct*16 + lrow;
                float bb = b2s[col];
                int rowb = wr*64 + rt*16 + quad*4;
#pragma unroll
                for (int r = 0; r < 4; r++) {
                    float v = fmaxf(acc[rt][ct][r] + bb, 0.f);
                    h2s[(rowb + r)*136 + col] = (f16)v;
                }
            }
        __syncthreads();
        // burst store: full rows, 16B chunks, global chunk index XOR row&15
        size_t gbase = ((size_t)P0 + (size_t)mt*128) * 128;
#pragma unroll
        for (int i = 0; i < 8; i++) {
            int e = i*256 + tid;
            int row = e >> 4, c = e & 15;
            f16x8 v = *(const f16x8*)(h2s + row*136 + c*8);
            *(f16x8*)(h2 + gbase + (size_t)row*128 + ((c ^ (row & 15)) * 8)) = v;
        }
    }
}

// ---------------------------------------------------------------------------
// Kernel B: h2[1024x128] @ W3[128x1024] (f16 MFMA), bias+relu+max over points
// -> g[B][1024].  Block = (b, 256-col strip): halves h2 re-reads vs 128-col.
// Decode b = i&255, nb = i>>8  =>  same-b blocks share i%8 => same XCD =>
// h2 tile L2 reuse.  Wave owns a 64-col strip over all 128 rows, processed
// in two 64-row halves to keep VGPR ~180 (no spill at 2 waves/SIMD).
// ---------------------------------------------------------------------------
__global__ __launch_bounds__(256, 2) void pointnet_l3_max(
    const f16* __restrict__ h2,    // [B*1024][128] swizzled chunks
    const f16* __restrict__ w3t,   // [1024][128]
    const float* __restrict__ b3,  // [1024]
    float* __restrict__ g)         // [B][1024]
{
    __shared__ __align__(16) f16 atile[128 * 128];  // 32 KB

    int i  = blockIdx.x;
    int b  = i & 255, nb = i >> 8;   // nb 0..3
    int tid = threadIdx.x;
    int lane = tid & 63, wid = tid >> 6;
    int lrow = lane & 15, quad = lane >> 4;
    int col0 = nb*256 + wid*64;

    // B-fragments: 4 ct x 4 kc, 64 VGPR, whole K resident
    f16x8 bf[4][4];
#pragma unroll
    for (int ct = 0; ct < 4; ct++)
#pragma unroll
        for (int kc = 0; kc < 4; kc++)
            bf[ct][kc] = *(const f16x8*)(w3t + (size_t)(col0 + ct*16 + lrow)*128 + kc*32 + quad*8);

    float cmax[4] = {-3.0e38f, -3.0e38f, -3.0e38f, -3.0e38f};
    const f16* abase = h2 + (size_t)b * 1024 * 128;

    for (int m0 = 0; m0 < 1024; m0 += 128) {
        __syncthreads();
        {
            const f16* gsrc = abase + (size_t)m0 * 128;
#pragma unroll
            for (int s = 0; s < 8; s++) {
                int chunk = wid*512 + s*64 + lane;
                glds16(gsrc + chunk*8, atile + (wid*512 + s*64)*8);
            }
        }
        __syncthreads();

#pragma unroll
        for (int half = 0; half < 2; half++) {
            f32x4 acc[4][4];
#pragma unroll
            for (int rt = 0; rt < 4; rt++)
#pragma unroll
                for (int ct = 0; ct < 4; ct++)
                    acc[rt][ct] = (f32x4){0.f, 0.f, 0.f, 0.f};
#pragma unroll
            for (int kc = 0; kc < 4; kc++) {
                f16x8 af[4];
#pragma unroll
                for (int rt = 0; rt < 4; rt++) {
                    int row  = half*64 + rt*16 + lrow;
                    int slot = (kc*4 + quad) ^ lrow;   // un-swizzle
                    af[rt] = *(const f16x8*)(atile + row*128 + slot*8);
                }
#pragma unroll
                for (int rt = 0; rt < 4; rt++)
#pragma unroll
                    for (int ct = 0; ct < 4; ct++)
                        acc[rt][ct] = __builtin_amdgcn_mfma_f32_16x16x32_f16(af[rt], bf[ct][kc], acc[rt][ct], 0, 0, 0);
            }
#pragma unroll
            for (int rt = 0; rt < 4; rt++)
#pragma unroll
                for (int ct = 0; ct < 4; ct++)
#pragma unroll
                    for (int r = 0; r < 4; r++)
                        cmax[ct] = fmaxf(cmax[ct], acc[rt][ct][r]);
        }
    }

    // all 128 rows handled within the wave; reduce across quads only
#pragma unroll
    for (int ct = 0; ct < 4; ct++) {
        cmax[ct] = fmaxf(cmax[ct], __shfl_xor(cmax[ct], 16, 64));
        cmax[ct] = fmaxf(cmax[ct], __shfl_xor(cmax[ct], 32, 64));
    }
    if (quad == 0) {
#pragma unroll
        for (int ct = 0; ct < 4; ct++) {
            int cg = col0 + ct*16 + lrow;
            g[(size_t)b*1024 + cg] = fmaxf(cmax[ct] + b3[cg], 0.f);
        }
    }
}

// ---------------------------------------------------------------------------
// Head layer 1 partials: zp1[kc][b][c] = sum_{k in chunk} g[b][k]*Wh1[k][c].
// Grid (cb=2, bb=64, kc=4) = 512 blocks; block 256 thr; 4 batches/block.
// ---------------------------------------------------------------------------
__global__ __launch_bounds__(256) void head_l1(
    const float* __restrict__ g, const float* __restrict__ Wh1,
    float* __restrict__ zp1)
{
    __shared__ float gs4[4][256];
    int cb = blockIdx.x, bb = blockIdx.y, kc = blockIdx.z;
    int tid = threadIdx.x;
    int b0 = bb * 4;
    int kbase = kc * 256;
#pragma unroll
    for (int j = 0; j < 4; j++) {
        int i = tid + j*256;
        gs4[i >> 8][i & 255] = g[(size_t)(b0 + (i >> 8))*1024 + kbase + (i & 255)];
    }
    __syncthreads();

    int c = cb*256 + tid;
    float acc[4] = {0.f, 0.f, 0.f, 0.f};
#pragma unroll 1
    for (int k = 0; k < 256; k += 8) {
        float w[8];
#pragma unroll
        for (int j = 0; j < 8; j++) w[j] = Wh1[(size_t)(kbase+k+j)*512 + c];
#pragma unroll
        for (int r = 0; r < 4; r++) {
            float4 a = *(const float4*)&gs4[r][k];
            float4 bq = *(const float4*)&gs4[r][k+4];
            acc[r] = fmaf(a.x, w[0], acc[r]);
            acc[r] = fmaf(a.y, w[1], acc[r]);
            acc[r] = fmaf(a.z, w[2], acc[r]);
            acc[r] = fmaf(a.w, w[3], acc[r]);
            acc[r] = fmaf(bq.x, w[4], acc[r]);
            acc[r] = fmaf(bq.y, w[5], acc[r]);
            acc[r] = fmaf(bq.z, w[6], acc[r]);
            acc[r] = fmaf(bq.w, w[7], acc[r]);
        }
    }
#pragma unroll
    for (int r = 0; r < 4; r++)
        zp1[((size_t)kc*256 + b0 + r)*512 + c] = acc[r];
}

// ---------------------------------------------------------------------------
// Head layer 2 partials, z1-reduce fused into staging.
// Grid (bb=128, kc2=4) = 512 blocks; block 256; 2 batches/block.
// ---------------------------------------------------------------------------
__global__ __launch_bounds__(256) void head_l2(
    const float* __restrict__ zp1, const float* __restrict__ bh1,
    const float* __restrict__ Wh2, float* __restrict__ zp2)
{
    __shared__ float z1s[2][128];
    int bb = blockIdx.x, kc2 = blockIdx.y;
    int tid = threadIdx.x;
    int b0 = bb * 2;
    int kb = kc2 * 128;
    {
        int row = tid >> 7, kk = tid & 127;
        int col = kb + kk;
        float v = bh1[col];
#pragma unroll
        for (int j = 0; j < 4; j++)
            v += zp1[((size_t)j*256 + b0 + row)*512 + col];
        z1s[row][kk] = fmaxf(v, 0.f);
    }
    __syncthreads();

    int c = tid;
    float acc0 = 0.f, acc1 = 0.f;
#pragma unroll 1
    for (int k = 0; k < 128; k += 8) {
        float w[8];
#pragma unroll
        for (int j = 0; j < 8; j++) w[j] = Wh2[(size_t)(kb+k+j)*256 + c];
        float4 a0 = *(const float4*)&z1s[0][k];
        float4 a1 = *(const float4*)&z1s[0][k+4];
        float4 d0 = *(const float4*)&z1s[1][k];
        float4 d1 = *(const float4*)&z1s[1][k+4];
        acc0 = fmaf(a0.x, w[0], acc0);  acc1 = fmaf(d0.x, w[0], acc1);
        acc0 = fmaf(a0.y, w[1], acc0);  acc1 = fmaf(d0.y, w[1], acc1);
        acc0 = fmaf(a0.z, w[2], acc0);  acc1 = fmaf(d0.z, w[2], acc1);
        acc0 = fmaf(a0.w, w[3], acc0);  acc1 = fmaf(d0.w, w[3], acc1);
        acc0 = fmaf(a1.x, w[4], acc0);  acc1 = fmaf(d1.x, w[4], acc1);
        acc0 = fmaf(a1.y, w[5], acc0);  acc1 = fmaf(d1.y, w[5], acc1);
        acc0 = fmaf(a1.z, w[6], acc0);  acc1 = fmaf(d1.z, w[6], acc1);
        acc0 = fmaf(a1.w, w[7], acc0);  acc1 = fmaf(d1.w, w[7], acc1);
    }
    zp2[((size_t)kc2*256 + b0    )*256 + c] = acc0;
    zp2[((size_t)kc2*256 + b0 + 1)*256 + c] = acc1;
}

// ---------------------------------------------------------------------------
// SVD -> SO(3) projection, fp64 Jacobi on M^T M (per-thread serial)
// ---------------------------------------------------------------------------
__device__ inline void jrot(double S[3][3], double V[3][3], int p, int q)
{
    double apq = S[p][q];
    if (fabs(apq) < 1e-36) return;
    double tau = (S[q][q] - S[p][p]) / (2.0 * apq);
    double t = (tau >= 0.0 ? 1.0 : -1.0) / (fabs(tau) + sqrt(1.0 + tau*tau));
    double c = 1.0 / sqrt(1.0 + t*t);
    double s = t * c;
    for (int k = 0; k < 3; k++) {
        double skp = S[k][p], skq = S[k][q];
        S[k][p] = c*skp - s*skq;  S[k][q] = s*skp + c*skq;
    }
    for (int k = 0; k < 3; k++) {
        double spk = S[p][k], sqk = S[q][k];
        S[p][k] = c*spk - s*sqk;  S[q][k] = s*spk + c*sqk;
    }
    for (int k = 0; k < 3; k++) {
        double vkp = V[k][p], vkq = V[k][q];
        V[k][p] = c*vkp - s*vkq;  V[k][q] = s*vkp + c*vkq;
    }
}

__device__ void svd_so3(const float* Mf, float* Rout)
{
    double M[3][3], S[3][3], V[3][3];
    for (int i = 0; i < 3; i++)
        for (int j = 0; j < 3; j++) M[i][j] = (double)Mf[3*i+j];
    for (int i = 0; i < 3; i++)
        for (int j = 0; j < 3; j++)
            S[i][j] = M[0][i]*M[0][j] + M[1][i]*M[1][j] + M[2][i]*M[2][j];
    for (int i = 0; i < 3; i++)
        for (int j = 0; j < 3; j++) V[i][j] = (i == j) ? 1.0 : 0.0;
    for (int it = 0; it < 10; it++) {
        jrot(S, V, 0, 1); jrot(S, V, 0, 2); jrot(S, V, 1, 2);
    }
    double lam[3] = {S[0][0], S[1][1], S[2][2]};
    int i0 = 0, i1 = 1, i2 = 2, tt;
    if (lam[i0] < lam[i1]) { tt = i0; i0 = i1; i1 = tt; }
    if (lam[i0] < lam[i2]) { tt = i0; i0 = i2; i2 = tt; }
    if (lam[i1] < lam[i2]) { tt = i1; i1 = i2; i2 = tt; }
    double v0[3], v1[3], v2[3];
    for (int k = 0; k < 3; k++) { v0[k] = V[k][i0]; v1[k] = V[k][i1]; v2[k] = V[k][i2]; }
    double u1[3], u2[3], u3[3];
    for (int i = 0; i < 3; i++) u1[i] = M[i][0]*v0[0] + M[i][1]*v0[1] + M[i][2]*v0[2];
    double n1 = sqrt(u1[0]*u1[0] + u1[1]*u1[1] + u1[2]*u1[2]) + 1e-300;
    for (int i = 0; i < 3; i++) u1[i] /= n1;
    for (int i = 0; i < 3; i++) u2[i] = M[i][0]*v1[0] + M[i][1]*v1[1] + M[i][2]*v1[2];
    double d12 = u1[0]*u2[0] + u1[1]*u2[1] + u1[2]*u2[2];
    for (int i = 0; i < 3; i++) u2[i] -= d12*u1[i];
    double n2 = sqrt(u2[0]*u2[0] + u2[1]*u2[1] + u2[2]*u2[2]) + 1e-300;
    for (int i = 0; i < 3; i++) u2[i] /= n2;
    u3[0] = u1[1]*u2[2] - u1[2]*u2[1];
    u3[1] = u1[2]*u2[0] - u1[0]*u2[2];
    u3[2] = u1[0]*u2[1] - u1[1]*u2[0];
    double c12x = v1[1]*v2[2] - v1[2]*v2[1];
    double c12y = v1[2]*v2[0] - v1[0]*v2[2];
    double c12z = v1[0]*v2[1] - v1[1]*v2[0];
    double detV = v0[0]*c12x + v0[1]*c12y + v0[2]*c12z;
    for (int i = 0; i < 3; i++)
        for (int j = 0; j < 3; j++)
            Rout[3*i+j] = (float)(u1[i]*v0[j] + u2[i]*v1[j] + detV*u3[i]*v2[j]);
}

// ---------------------------------------------------------------------------
// Head tail: z2-reduce + (z2 @ Wh3 + bh3) + SVD. Wh3 staged in LDS.
// 8 batches/block, 32 blocks x 128 threads.
// ---------------------------------------------------------------------------
__global__ __launch_bounds__(128) void head_l3_svd(
    const float* __restrict__ zp2, const float* __restrict__ bh2,
    const float* __restrict__ Wh3, const float* __restrict__ bh3,
    float* __restrict__ out)
{
    __shared__ float z2s[8][256];
    __shared__ float wh3s[2304];
    __shared__ float raws[8][12];
    int b0 = blockIdx.x * 8;
    int tid = threadIdx.x;

    for (int i = tid; i < 2304; i += 128) wh3s[i] = Wh3[i];
    for (int i = tid; i < 8*256; i += 128) {
        int row = i >> 8, kk = i & 255;
        float v = bh2[kk];
#pragma unroll
        for (int j = 0; j < 4; j++)
            v += zp2[((size_t)j*256 + b0 + row)*256 + kk];
        z2s[row][kk] = fmaxf(v, 0.f);
    }
    __syncthreads();

    if (tid < 72) {
        int r = tid / 9, c = tid % 9;
        float acc = bh3[c];
#pragma unroll 8
        for (int k = 0; k < 256; k++) acc = fmaf(z2s[r][k], wh3s[k*9 + c], acc);
        raws[r][c] = acc;
    }
    __syncthreads();

    if (tid < 8) svd_so3(&raws[tid][0], out + (size_t)(b0 + tid)*9);
}

// ---------------------------------------------------------------------------
extern "C" void kernel_launch(void* const* d_in, const int* in_sizes, int n_in,
                              void* d_out, int out_size, void* d_ws, size_t ws_size,
                              hipStream_t stream)
{
    const float* x   = (const float*)d_in[0];
    const float* W1  = (const float*)d_in[1];
    const float* b1  = (const float*)d_in[2];
    const float* W2  = (const float*)d_in[3];
    const float* b2  = (const float*)d_in[4];
    const float* W3  = (const float*)d_in[5];
    const float* b3  = (const float*)d_in[6];
    const float* Wh1 = (const float*)d_in[7];
    const float* bh1 = (const float*)d_in[8];
    const float* Wh2 = (const float*)d_in[9];
    const float* bh2 = (const float*)d_in[10];
    const float* Wh3 = (const float*)d_in[11];
    const float* bh3 = (const float*)d_in[12];
    float* out = (float*)d_out;

    char* ws = (char*)d_ws;
    f16*   h2  = (f16*)ws;                                  // 64 MB
    f16*   w3t = (f16*)(ws + (size_t)67108864);             // 256 KB
    f16*   w2t = (f16*)(ws + (size_t)67108864 + 262144);    // 16 KB
    float* g   = (float*)(ws + (size_t)67108864 + 262144 + 16384);             // 1 MB
    float* zp1 = (float*)(ws + (size_t)67108864 + 262144 + 16384 + 1048576);   // 2 MB
    float* zp2 = (float*)(ws + (size_t)67108864 + 262144 + 16384 + 1048576 + 2097152);  // 1 MB

    prep_wt<<<34, 256, 0, stream>>>(W3, W2, w3t, w2t);
    pointnet_l12<<<512, 256, 0, stream>>>(x, W1, b1, w2t, b2, h2);
    pointnet_l3_max<<<1024, 256, 0, stream>>>(h2, w3t, b3, g);
    dim3 gridH1(2, 64, 4);
    head_l1<<<gridH1, 256, 0, stream>>>(g, Wh1, zp1);
    dim3 gridH2(128, 4);
    head_l2<<<gridH2, 256, 0, stream>>>(zp1, bh1, Wh2, zp2);
    head_l3_svd<<<32, 128, 0, stream>>>(zp2, bh2, Wh3, bh3, out);
}

// Round 5
// 189.362 us; speedup vs baseline: 2.0835x; 1.0110x over previous
//
#include <hip/hip_runtime.h>
#include <math.h>

typedef _Float16 f16;
typedef _Float16 f16x8 __attribute__((ext_vector_type(8)));
typedef float f32x4 __attribute__((ext_vector_type(4)));

// async global->LDS, 16B per lane. LDS dest = wave-uniform base + lane*16.
__device__ __forceinline__ void glds16(const void* g, void* l) {
    __builtin_amdgcn_global_load_lds(
        (const __attribute__((address_space(1))) unsigned int*)g,
        (__attribute__((address_space(3))) unsigned int*)l, 16, 0, 0);
}

// ---------------------------------------------------------------------------
// Kernel A (MFMA): per-point MLP layers 1-2.  Block = 512 points (4 m-tiles
// of 128).  h1 fragments built in-register, layer2 via f16 MFMA with W2
// B-fragments resident (loaded directly from fp32 W2, cvt once).  Epilogue:
// bias+relu+cvt, LDS transpose, burst store with chunk^row swizzle so kernel
// B can global_load_lds contiguously.  Full-row bursts -> no partial-line
// write amplification.
// ---------------------------------------------------------------------------
__global__ __launch_bounds__(256, 2) void pointnet_l12(
    const float* __restrict__ x,
    const float* __restrict__ W1, const float* __restrict__ b1,
    const float* __restrict__ W2, const float* __restrict__ b2,
    f16* __restrict__ h2)
{
    __shared__ float xs[512*3];                    // 6 KB
    __shared__ float w1s[192], b1s[64], b2s[128];  // 1.5 KB
    __shared__ __align__(16) f16 h2s[128*136];     // 34.8 KB, +8 pad per row

    int tid = threadIdx.x;
    int P0 = blockIdx.x * 512;
    for (int i = tid; i < 1536; i += 256) xs[i] = x[(size_t)P0*3 + i];
    if (tid < 192) w1s[tid] = W1[tid];
    else b1s[tid - 192] = b1[tid - 192];
    if (tid < 128) b2s[tid] = b2[tid];

    int lane = tid & 63, wid = tid >> 6;
    int wr = wid & 1, wc = wid >> 1;
    int lrow = lane & 15, quad = lane >> 4;

    // B-fragments direct from fp32 W2 [64 k][128 n] (L2-resident, once/block)
    f16x8 bf[4][2];
#pragma unroll
    for (int ct = 0; ct < 4; ct++)
#pragma unroll
        for (int kc = 0; kc < 2; kc++) {
            int col = wc*64 + ct*16 + lrow;
#pragma unroll
            for (int j = 0; j < 8; j++)
                bf[ct][kc][j] = (f16)W2[(size_t)(kc*32 + quad*8 + j)*128 + col];
        }

    __syncthreads();

    for (int mt = 0; mt < 4; mt++) {
        f32x4 acc[4][4];
#pragma unroll
        for (int rt = 0; rt < 4; rt++)
#pragma unroll
            for (int ct = 0; ct < 4; ct++)
                acc[rt][ct] = (f32x4){0.f, 0.f, 0.f, 0.f};

#pragma unroll
        for (int kc = 0; kc < 2; kc++) {
            float wa[8], wb[8], wcv[8], bv[8];
#pragma unroll
            for (int j = 0; j < 8; j++) {
                int k = kc*32 + quad*8 + j;
                wa[j] = w1s[k]; wb[j] = w1s[64+k]; wcv[j] = w1s[128+k]; bv[j] = b1s[k];
            }
            f16x8 af[4];
#pragma unroll
            for (int rt = 0; rt < 4; rt++) {
                int p = mt*128 + wr*64 + rt*16 + lrow;
                float x0 = xs[p*3], x1 = xs[p*3+1], x2 = xs[p*3+2];
#pragma unroll
                for (int j = 0; j < 8; j++) {
                    float v = fmaf(x2, wcv[j], fmaf(x1, wb[j], fmaf(x0, wa[j], bv[j])));
                    af[rt][j] = (f16)fmaxf(v, 0.f);
                }
            }
#pragma unroll
            for (int rt = 0; rt < 4; rt++)
#pragma unroll
                for (int ct = 0; ct < 4; ct++)
                    acc[rt][ct] = __builtin_amdgcn_mfma_f32_16x16x32_f16(af[rt], bf[ct][kc], acc[rt][ct], 0, 0, 0);
        }

        __syncthreads();   // previous tile's h2s readers done
#pragma unroll
        for (int rt = 0; rt < 4; rt++)
#pragma unroll
            for (int ct = 0; ct < 4; ct++) {
                int col  = wc*64 + ct*16 + lrow;
                float bb = b2s[col];
                int rowb = wr*64 + rt*16 + quad*4;
#pragma unroll
                for (int r = 0; r < 4; r++) {
                    float v = fmaxf(acc[rt][ct][r] + bb, 0.f);
                    h2s[(rowb + r)*136 + col] = (f16)v;
                }
            }
        __syncthreads();
        // burst store: full rows, 16B chunks, global chunk index XOR row&15
        size_t gbase = ((size_t)P0 + (size_t)mt*128) * 128;
#pragma unroll
        for (int i = 0; i < 8; i++) {
            int e = i*256 + tid;
            int row = e >> 4, c = e & 15;
            f16x8 v = *(const f16x8*)(h2s + row*136 + c*8);
            *(f16x8*)(h2 + gbase + (size_t)row*128 + ((c ^ (row & 15)) * 8)) = v;
        }
    }
}

// ---------------------------------------------------------------------------
// Kernel B: h2[1024x128] @ W3[128x1024] (f16 MFMA), bias+relu+max over points
// -> g[B][1024].  Block = (b, 256-col strip).  Decode b=i&255, nb=i>>8 =>
// same-b blocks share i%8 => same XCD => h2 L2 reuse.  B-fragments loaded
// directly from fp32 W3 (once per block).  A-tile DOUBLE-BUFFERED via
// global_load_lds: prefetch of tile m+1 issued right after the barrier, in
// flight during tile m's MFMA -> the vmcnt(0) drain at the next barrier is
// covered by compute.
// ---------------------------------------------------------------------------
__global__ __launch_bounds__(256, 2) void pointnet_l3_max(
    const f16* __restrict__ h2,    // [B*1024][128] swizzled chunks
    const float* __restrict__ W3,  // [128][1024] fp32
    const float* __restrict__ b3,  // [1024]
    float* __restrict__ g)         // [B][1024]
{
    __shared__ __align__(16) f16 atile[2][128 * 128];  // 2 x 32 KB

    int i  = blockIdx.x;
    int b  = i & 255, nb = i >> 8;   // nb 0..3
    int tid = threadIdx.x;
    int lane = tid & 63, wid = tid >> 6;
    int lrow = lane & 15, quad = lane >> 4;
    int col0 = nb*256 + wid*64;

    // B-fragments direct from fp32 W3 [128 k][1024 n] (L2-resident)
    f16x8 bf[4][4];
#pragma unroll
    for (int ct = 0; ct < 4; ct++)
#pragma unroll
        for (int kc = 0; kc < 4; kc++) {
            int col = col0 + ct*16 + lrow;
#pragma unroll
            for (int j = 0; j < 8; j++)
                bf[ct][kc][j] = (f16)W3[(size_t)(kc*32 + quad*8 + j)*1024 + col];
        }

    float cmax[4] = {-3.0e38f, -3.0e38f, -3.0e38f, -3.0e38f};
    const f16* abase = h2 + (size_t)b * 1024 * 128;

    // prologue: prefetch tile 0 into buffer 0
    {
        const f16* gsrc = abase;
#pragma unroll
        for (int s = 0; s < 8; s++)
            glds16(gsrc + (wid*512 + s*64 + lane)*8, atile[0] + (wid*512 + s*64)*8);
    }

    int cur = 0;
    for (int m0 = 0; m0 < 1024; m0 += 128) {
        __syncthreads();   // prefetch(cur) landed; prior reads of other buf done
        if (m0 + 128 < 1024) {
            const f16* gsrc = abase + (size_t)(m0 + 128) * 128;
            f16* ldst = atile[cur ^ 1];
#pragma unroll
            for (int s = 0; s < 8; s++)
                glds16(gsrc + (wid*512 + s*64 + lane)*8, ldst + (wid*512 + s*64)*8);
        }

        const f16* at = atile[cur];
#pragma unroll
        for (int half = 0; half < 2; half++) {
            f32x4 acc[4][4];
#pragma unroll
            for (int rt = 0; rt < 4; rt++)
#pragma unroll
                for (int ct = 0; ct < 4; ct++)
                    acc[rt][ct] = (f32x4){0.f, 0.f, 0.f, 0.f};
#pragma unroll
            for (int kc = 0; kc < 4; kc++) {
                f16x8 af[4];
#pragma unroll
                for (int rt = 0; rt < 4; rt++) {
                    int row  = half*64 + rt*16 + lrow;
                    int slot = (kc*4 + quad) ^ lrow;   // un-swizzle
                    af[rt] = *(const f16x8*)(at + row*128 + slot*8);
                }
#pragma unroll
                for (int rt = 0; rt < 4; rt++)
#pragma unroll
                    for (int ct = 0; ct < 4; ct++)
                        acc[rt][ct] = __builtin_amdgcn_mfma_f32_16x16x32_f16(af[rt], bf[ct][kc], acc[rt][ct], 0, 0, 0);
            }
#pragma unroll
            for (int rt = 0; rt < 4; rt++)
#pragma unroll
                for (int ct = 0; ct < 4; ct++)
#pragma unroll
                    for (int r = 0; r < 4; r++)
                        cmax[ct] = fmaxf(cmax[ct], acc[rt][ct][r]);
        }
        cur ^= 1;
    }

#pragma unroll
    for (int ct = 0; ct < 4; ct++) {
        cmax[ct] = fmaxf(cmax[ct], __shfl_xor(cmax[ct], 16, 64));
        cmax[ct] = fmaxf(cmax[ct], __shfl_xor(cmax[ct], 32, 64));
    }
    if (quad == 0) {
#pragma unroll
        for (int ct = 0; ct < 4; ct++) {
            int cg = col0 + ct*16 + lrow;
            g[(size_t)b*1024 + cg] = fmaxf(cmax[ct] + b3[cg], 0.f);
        }
    }
}

// ---------------------------------------------------------------------------
// Head layer 1 partials: zp1[kc][b][c] = sum_{k in chunk} g[b][k]*Wh1[k][c].
// Grid (cb=2, bb=64, kc=4) = 512 blocks; block 256 thr; 4 batches/block.
// ---------------------------------------------------------------------------
__global__ __launch_bounds__(256) void head_l1(
    const float* __restrict__ g, const float* __restrict__ Wh1,
    float* __restrict__ zp1)
{
    __shared__ float gs4[4][256];
    int cb = blockIdx.x, bb = blockIdx.y, kc = blockIdx.z;
    int tid = threadIdx.x;
    int b0 = bb * 4;
    int kbase = kc * 256;
#pragma unroll
    for (int j = 0; j < 4; j++) {
        int i = tid + j*256;
        gs4[i >> 8][i & 255] = g[(size_t)(b0 + (i >> 8))*1024 + kbase + (i & 255)];
    }
    __syncthreads();

    int c = cb*256 + tid;
    float acc[4] = {0.f, 0.f, 0.f, 0.f};
#pragma unroll 1
    for (int k = 0; k < 256; k += 8) {
        float w[8];
#pragma unroll
        for (int j = 0; j < 8; j++) w[j] = Wh1[(size_t)(kbase+k+j)*512 + c];
#pragma unroll
        for (int r = 0; r < 4; r++) {
            float4 a = *(const float4*)&gs4[r][k];
            float4 bq = *(const float4*)&gs4[r][k+4];
            acc[r] = fmaf(a.x, w[0], acc[r]);
            acc[r] = fmaf(a.y, w[1], acc[r]);
            acc[r] = fmaf(a.z, w[2], acc[r]);
            acc[r] = fmaf(a.w, w[3], acc[r]);
            acc[r] = fmaf(bq.x, w[4], acc[r]);
            acc[r] = fmaf(bq.y, w[5], acc[r]);
            acc[r] = fmaf(bq.z, w[6], acc[r]);
            acc[r] = fmaf(bq.w, w[7], acc[r]);
        }
    }
#pragma unroll
    for (int r = 0; r < 4; r++)
        zp1[((size_t)kc*256 + b0 + r)*512 + c] = acc[r];
}

// ---------------------------------------------------------------------------
// Head layer 2 partials, z1-reduce fused into staging.
// Grid (bb=128, kc2=4) = 512 blocks; block 256; 2 batches/block.
// ---------------------------------------------------------------------------
__global__ __launch_bounds__(256) void head_l2(
    const float* __restrict__ zp1, const float* __restrict__ bh1,
    const float* __restrict__ Wh2, float* __restrict__ zp2)
{
    __shared__ float z1s[2][128];
    int bb = blockIdx.x, kc2 = blockIdx.y;
    int tid = threadIdx.x;
    int b0 = bb * 2;
    int kb = kc2 * 128;
    {
        int row = tid >> 7, kk = tid & 127;
        int col = kb + kk;
        float v = bh1[col];
#pragma unroll
        for (int j = 0; j < 4; j++)
            v += zp1[((size_t)j*256 + b0 + row)*512 + col];
        z1s[row][kk] = fmaxf(v, 0.f);
    }
    __syncthreads();

    int c = tid;
    float acc0 = 0.f, acc1 = 0.f;
#pragma unroll 1
    for (int k = 0; k < 128; k += 8) {
        float w[8];
#pragma unroll
        for (int j = 0; j < 8; j++) w[j] = Wh2[(size_t)(kb+k+j)*256 + c];
        float4 a0 = *(const float4*)&z1s[0][k];
        float4 a1 = *(const float4*)&z1s[0][k+4];
        float4 d0 = *(const float4*)&z1s[1][k];
        float4 d1 = *(const float4*)&z1s[1][k+4];
        acc0 = fmaf(a0.x, w[0], acc0);  acc1 = fmaf(d0.x, w[0], acc1);
        acc0 = fmaf(a0.y, w[1], acc0);  acc1 = fmaf(d0.y, w[1], acc1);
        acc0 = fmaf(a0.z, w[2], acc0);  acc1 = fmaf(d0.z, w[2], acc1);
        acc0 = fmaf(a0.w, w[3], acc0);  acc1 = fmaf(d0.w, w[3], acc1);
        acc0 = fmaf(a1.x, w[4], acc0);  acc1 = fmaf(d1.x, w[4], acc1);
        acc0 = fmaf(a1.y, w[5], acc0);  acc1 = fmaf(d1.y, w[5], acc1);
        acc0 = fmaf(a1.z, w[6], acc0);  acc1 = fmaf(d1.z, w[6], acc1);
        acc0 = fmaf(a1.w, w[7], acc0);  acc1 = fmaf(d1.w, w[7], acc1);
    }
    zp2[((size_t)kc2*256 + b0    )*256 + c] = acc0;
    zp2[((size_t)kc2*256 + b0 + 1)*256 + c] = acc1;
}

// ---------------------------------------------------------------------------
// SVD -> SO(3) projection, fp64 Jacobi on M^T M (per-thread serial)
// ---------------------------------------------------------------------------
__device__ inline void jrot(double S[3][3], double V[3][3], int p, int q)
{
    double apq = S[p][q];
    if (fabs(apq) < 1e-36) return;
    double tau = (S[q][q] - S[p][p]) / (2.0 * apq);
    double t = (tau >= 0.0 ? 1.0 : -1.0) / (fabs(tau) + sqrt(1.0 + tau*tau));
    double c = 1.0 / sqrt(1.0 + t*t);
    double s = t * c;
    for (int k = 0; k < 3; k++) {
        double skp = S[k][p], skq = S[k][q];
        S[k][p] = c*skp - s*skq;  S[k][q] = s*skp + c*skq;
    }
    for (int k = 0; k < 3; k++) {
        double spk = S[p][k], sqk = S[q][k];
        S[p][k] = c*spk - s*sqk;  S[q][k] = s*spk + c*sqk;
    }
    for (int k = 0; k < 3; k++) {
        double vkp = V[k][p], vkq = V[k][q];
        V[k][p] = c*vkp - s*vkq;  V[k][q] = s*vkp + c*vkq;
    }
}

__device__ void svd_so3(const float* Mf, float* Rout)
{
    double M[3][3], S[3][3], V[3][3];
    for (int i = 0; i < 3; i++)
        for (int j = 0; j < 3; j++) M[i][j] = (double)Mf[3*i+j];
    for (int i = 0; i < 3; i++)
        for (int j = 0; j < 3; j++)
            S[i][j] = M[0][i]*M[0][j] + M[1][i]*M[1][j] + M[2][i]*M[2][j];
    for (int i = 0; i < 3; i++)
        for (int j = 0; j < 3; j++) V[i][j] = (i == j) ? 1.0 : 0.0;
    for (int it = 0; it < 10; it++) {
        jrot(S, V, 0, 1); jrot(S, V, 0, 2); jrot(S, V, 1, 2);
    }
    double lam[3] = {S[0][0], S[1][1], S[2][2]};
    int i0 = 0, i1 = 1, i2 = 2, tt;
    if (lam[i0] < lam[i1]) { tt = i0; i0 = i1; i1 = tt; }
    if (lam[i0] < lam[i2]) { tt = i0; i0 = i2; i2 = tt; }
    if (lam[i1] < lam[i2]) { tt = i1; i1 = i2; i2 = tt; }
    double v0[3], v1[3], v2[3];
    for (int k = 0; k < 3; k++) { v0[k] = V[k][i0]; v1[k] = V[k][i1]; v2[k] = V[k][i2]; }
    double u1[3], u2[3], u3[3];
    for (int i = 0; i < 3; i++) u1[i] = M[i][0]*v0[0] + M[i][1]*v0[1] + M[i][2]*v0[2];
    double n1 = sqrt(u1[0]*u1[0] + u1[1]*u1[1] + u1[2]*u1[2]) + 1e-300;
    for (int i = 0; i < 3; i++) u1[i] /= n1;
    for (int i = 0; i < 3; i++) u2[i] = M[i][0]*v1[0] + M[i][1]*v1[1] + M[i][2]*v1[2];
    double d12 = u1[0]*u2[0] + u1[1]*u2[1] + u1[2]*u2[2];
    for (int i = 0; i < 3; i++) u2[i] -= d12*u1[i];
    double n2 = sqrt(u2[0]*u2[0] + u2[1]*u2[1] + u2[2]*u2[2]) + 1e-300;
    for (int i = 0; i < 3; i++) u2[i] /= n2;
    u3[0] = u1[1]*u2[2] - u1[2]*u2[1];
    u3[1] = u1[2]*u2[0] - u1[0]*u2[2];
    u3[2] = u1[0]*u2[1] - u1[1]*u2[0];
    double c12x = v1[1]*v2[2] - v1[2]*v2[1];
    double c12y = v1[2]*v2[0] - v1[0]*v2[2];
    double c12z = v1[0]*v2[1] - v1[1]*v2[0];
    double detV = v0[0]*c12x + v0[1]*c12y + v0[2]*c12z;
    for (int i = 0; i < 3; i++)
        for (int j = 0; j < 3; j++)
            Rout[3*i+j] = (float)(u1[i]*v0[j] + u2[i]*v1[j] + detV*u3[i]*v2[j]);
}

// ---------------------------------------------------------------------------
// Head tail: z2-reduce + (z2 @ Wh3 + bh3) + SVD. Wh3 staged in LDS.
// 8 batches/block, 32 blocks x 128 threads.
// ---------------------------------------------------------------------------
__global__ __launch_bounds__(128) void head_l3_svd(
    const float* __restrict__ zp2, const float* __restrict__ bh2,
    const float* __restrict__ Wh3, const float* __restrict__ bh3,
    float* __restrict__ out)
{
    __shared__ float z2s[8][256];
    __shared__ float wh3s[2304];
    __shared__ float raws[8][12];
    int b0 = blockIdx.x * 8;
    int tid = threadIdx.x;

    for (int i = tid; i < 2304; i += 128) wh3s[i] = Wh3[i];
    for (int i = tid; i < 8*256; i += 128) {
        int row = i >> 8, kk = i & 255;
        float v = bh2[kk];
#pragma unroll
        for (int j = 0; j < 4; j++)
            v += zp2[((size_t)j*256 + b0 + row)*256 + kk];
        z2s[row][kk] = fmaxf(v, 0.f);
    }
    __syncthreads();

    if (tid < 72) {
        int r = tid / 9, c = tid % 9;
        float acc = bh3[c];
#pragma unroll 8
        for (int k = 0; k < 256; k++) acc = fmaf(z2s[r][k], wh3s[k*9 + c], acc);
        raws[r][c] = acc;
    }
    __syncthreads();

    if (tid < 8) svd_so3(&raws[tid][0], out + (size_t)(b0 + tid)*9);
}

// ---------------------------------------------------------------------------
extern "C" void kernel_launch(void* const* d_in, const int* in_sizes, int n_in,
                              void* d_out, int out_size, void* d_ws, size_t ws_size,
                              hipStream_t stream)
{
    const float* x   = (const float*)d_in[0];
    const float* W1  = (const float*)d_in[1];
    const float* b1  = (const float*)d_in[2];
    const float* W2  = (const float*)d_in[3];
    const float* b2  = (const float*)d_in[4];
    const float* W3  = (const float*)d_in[5];
    const float* b3  = (const float*)d_in[6];
    const float* Wh1 = (const float*)d_in[7];
    const float* bh1 = (const float*)d_in[8];
    const float* Wh2 = (const float*)d_in[9];
    const float* bh2 = (const float*)d_in[10];
    const float* Wh3 = (const float*)d_in[11];
    const float* bh3 = (const float*)d_in[12];
    float* out = (float*)d_out;

    char* ws = (char*)d_ws;
    f16*   h2  = (f16*)ws;                                  // 64 MB
    float* g   = (float*)(ws + (size_t)67108864);           // 1 MB
    float* zp1 = (float*)(ws + (size_t)67108864 + 1048576);            // 2 MB
    float* zp2 = (float*)(ws + (size_t)67108864 + 1048576 + 2097152);  // 1 MB

    pointnet_l12<<<512, 256, 0, stream>>>(x, W1, b1, W2, b2, h2);
    pointnet_l3_max<<<1024, 256, 0, stream>>>(h2, W3, b3, g);
    dim3 gridH1(2, 64, 4);
    head_l1<<<gridH1, 256, 0, stream>>>(g, Wh1, zp1);
    dim3 gridH2(128, 4);
    head_l2<<<gridH2, 256, 0, stream>>>(zp1, bh1, Wh2, zp2);
    head_l3_svd<<<32, 128, 0, stream>>>(zp2, bh2, Wh3, bh3, out);
}